// Round 1
// baseline (1154.798 us; speedup 1.0000x reference)
//
#include <hip/hip_runtime.h>
#include <cstdint>
#include <cstddef>

#define BATCH 16
#define NCLS 80
#define NANCH 25200          // (80*80 + 40*40 + 20*20) * 3
#define NBINS 256
#define CAP 2048
#define KC 300               // pre-NMS candidates (K_CAND)
#define DET 100
#define PAD 2048             // bitonic sort size (>= CAP)
#define SCORE_T 0.25f
#define NMS_T 0.45f

__device__ __forceinline__ float sg(float x) { return 1.0f / (1.0f + expf(-x)); }

// anchor n within image b -> pointer to its 85 contiguous floats
__device__ __forceinline__ const float* anchor_base(const float* p3, const float* p4,
                                                    const float* p5, int b, int n) {
    if (n < 19200) return p3 + ((size_t)b * 19200 + n) * 85;
    if (n < 24000) return p4 + ((size_t)b * 4800 + (n - 19200)) * 85;
    return p5 + ((size_t)b * 1200 + (n - 24000)) * 85;
}

__global__ void k_zero(unsigned int* w, int n) {
    int i = blockIdx.x * blockDim.x + threadIdx.x;
    if (i < n) w[i] = 0u;
}

// Pass 1: per-image histogram of scores in (0.25, 1)
__global__ void k_hist(const float* __restrict__ p3, const float* __restrict__ p4,
                       const float* __restrict__ p5, unsigned int* __restrict__ hist) {
    __shared__ unsigned int lh[NBINS];
    const int BPI = (NANCH + 255) / 256;  // 99 blocks per image
    int b = blockIdx.x / BPI;
    int n = (blockIdx.x % BPI) * 256 + threadIdx.x;
    for (int i = threadIdx.x; i < NBINS; i += 256) lh[i] = 0u;
    __syncthreads();
    if (n < NANCH) {
        const float* base = anchor_base(p3, p4, p5, b, n);
        float obj = sg(base[4]);
        if (obj > SCORE_T) {   // logit = obj*cls <= obj, so obj<=T => no candidates
            for (int c = 0; c < NCLS; c++) {
                float s = obj * sg(base[5 + c]);
                if (s > SCORE_T) {
                    int bin = (int)((s - SCORE_T) * (NBINS / 0.75f));
                    bin = bin < 0 ? 0 : (bin > NBINS - 1 ? NBINS - 1 : bin);
                    atomicAdd(&lh[bin], 1u);
                }
            }
        }
    }
    __syncthreads();
    for (int i = threadIdx.x; i < NBINS; i += 256) {
        unsigned int v = lh[i];
        if (v) atomicAdd(&hist[b * NBINS + i], v);
    }
}

// Find bin T per image s.t. count(bins >= T) >= KC (suffix scan from top)
__global__ void k_thresh(const unsigned int* __restrict__ hist, int* __restrict__ binT) {
    int b = threadIdx.x;
    if (b < BATCH) {
        unsigned int cum = 0;
        int T = 0;
        for (int i = NBINS - 1; i >= 0; i--) {
            cum += hist[b * NBINS + i];
            if (cum >= KC) { T = i; break; }
        }
        binT[b] = T;
    }
}

// Pass 2: collect (score, flat_idx) for scores landing in bin >= T
__global__ void k_collect(const float* __restrict__ p3, const float* __restrict__ p4,
                          const float* __restrict__ p5, const int* __restrict__ binT,
                          unsigned int* __restrict__ cnt, uint2* __restrict__ cand) {
    const int BPI = (NANCH + 255) / 256;
    int b = blockIdx.x / BPI;
    int n = (blockIdx.x % BPI) * 256 + threadIdx.x;
    if (n >= NANCH) return;
    int T = binT[b];
    const float* base = anchor_base(p3, p4, p5, b, n);
    float obj = sg(base[4]);
    if (obj <= SCORE_T) return;
    for (int c = 0; c < NCLS; c++) {
        float s = obj * sg(base[5 + c]);
        if (s > SCORE_T) {
            int bin = (int)((s - SCORE_T) * (NBINS / 0.75f));
            bin = bin < 0 ? 0 : (bin > NBINS - 1 ? NBINS - 1 : bin);
            if (bin >= T) {
                unsigned int pos = atomicAdd(&cnt[b], 1u);
                if (pos < CAP)
                    cand[(size_t)b * CAP + pos] =
                        make_uint2(__float_as_uint(s), (unsigned int)(n * NCLS + c));
            }
        }
    }
}

// Per-image: sort candidates, decode top-300 boxes, NMS, write [100,6]
__global__ __launch_bounds__(512) void k_final(
    const float* __restrict__ p3, const float* __restrict__ p4, const float* __restrict__ p5,
    const float* __restrict__ anchors, const int* __restrict__ imshapes,
    const float* __restrict__ scalef, const unsigned int* __restrict__ cnt,
    const uint2* __restrict__ cand, float* __restrict__ out) {
    __shared__ float sv[PAD];
    __shared__ unsigned int si[PAD];
    __shared__ float4 bx[KC];
    __shared__ int lab[KC];
    __shared__ float sc[KC];
    __shared__ float ar[KC];
    __shared__ unsigned long long msk[KC * 5];
    __shared__ unsigned long long keep[5];
    __shared__ int order[DET];
    __shared__ int okept[DET];

    int b = blockIdx.x;
    int tid = threadIdx.x;
    int nc = (int)cnt[b];
    if (nc > CAP) nc = CAP;

    for (int i = tid; i < PAD; i += 512) {
        if (i < nc) {
            uint2 cc = cand[(size_t)b * CAP + i];
            sv[i] = __uint_as_float(cc.x);
            si[i] = cc.y;
        } else {
            sv[i] = -1e30f;
            si[i] = 0xffffffffu;
        }
    }
    __syncthreads();

    // bitonic sort: score desc, flat-idx asc (jax top_k tie-break)
    for (int k = 2; k <= PAD; k <<= 1) {
        for (int j = k >> 1; j > 0; j >>= 1) {
            for (int i = tid; i < PAD; i += 512) {
                int ixj = i ^ j;
                if (ixj > i) {
                    float s1 = sv[i], s2 = sv[ixj];
                    unsigned int i1 = si[i], i2 = si[ixj];
                    bool pre = (s1 > s2) || (s1 == s2 && i1 < i2);  // i precedes ixj
                    bool up = ((i & k) == 0);
                    if (pre != up) { sv[i] = s2; sv[ixj] = s1; si[i] = i2; si[ixj] = i1; }
                }
            }
            __syncthreads();
        }
    }

    int valid = nc < KC ? nc : KC;
    if (tid < KC) {
        int i = tid;
        if (i < valid) {
            unsigned int fi = si[i];
            int n = (int)(fi / NCLS), c = (int)(fi % NCLS);
            int lvl = (n < 19200) ? 0 : (n < 24000 ? 1 : 2);
            const int offl[3] = {0, 19200, 24000};
            const int Wl[3] = {80, 40, 20};
            const int cntl[3] = {19200, 4800, 1200};
            const float strl[3] = {8.f, 16.f, 32.f};
            const float* pp = lvl == 0 ? p3 : (lvl == 1 ? p4 : p5);
            int nl = n - offl[lvl];
            int a = nl % 3, cell = nl / 3;
            int gx = cell % Wl[lvl], gy = cell / Wl[lvl];
            const float* pb = pp + ((size_t)b * cntl[lvl] + nl) * 85;
            float s0 = sg(pb[0]), s1 = sg(pb[1]), s2 = sg(pb[2]), s3 = sg(pb[3]);
            float stride = strl[lvl];
            float aw = anchors[(lvl * 3 + a) * 2 + 0];
            float ah = anchors[(lvl * 3 + a) * 2 + 1];
            float cx = (2.0f * s0 - 0.5f + (float)gx) * stride;
            float cy = (2.0f * s1 - 0.5f + (float)gy) * stride;
            float bw = 4.0f * s2 * s2 * aw;
            float bh = 4.0f * s3 * s3 * ah;
            float hf = (float)imshapes[b * 2 + 0];
            float wf = (float)imshapes[b * 2 + 1];
            float x1 = cx - bw / 2.0f, y1 = cy - bh / 2.0f;
            float x2 = cx + bw / 2.0f, y2 = cy + bh / 2.0f;
            x1 = fminf(fmaxf(x1, 0.f), wf);
            y1 = fminf(fmaxf(y1, 0.f), hf);
            x2 = fminf(fmaxf(x2, 0.f), wf);
            y2 = fminf(fmaxf(y2, 0.f), hf);
            bx[i] = make_float4(x1, y1, x2, y2);
            lab[i] = c;
            sc[i] = sv[i];
            ar[i] = (x2 - x1) * (y2 - y1);
        } else {
            bx[i] = make_float4(0, 0, 0, 0);
            lab[i] = -1 - i;  // unique: never matches in NMS
            sc[i] = 0.f;
            ar[i] = 0.f;
        }
    }
    __syncthreads();

    // suppression bitmask rows: bit j of row i set iff j>i, same label, IoU>0.45
    // (class-offset boxes: offset 4096*Δlabel > 640 => cross-label IoU == 0)
    for (int t = tid; t < KC * 5; t += 512) {
        int i = t / 5, w = t % 5;
        float4 bi = bx[i];
        int li = lab[i];
        float ai = ar[i];
        unsigned long long m = 0ull;
        for (int tb = 0; tb < 64; tb++) {
            int j = w * 64 + tb;
            if (j < KC && j > i && lab[j] == li) {
                float4 bj = bx[j];
                float ltx = fmaxf(bi.x, bj.x), lty = fmaxf(bi.y, bj.y);
                float rbx = fminf(bi.z, bj.z), rby = fminf(bi.w, bj.w);
                float iw = fmaxf(rbx - ltx, 0.f), ih = fmaxf(rby - lty, 0.f);
                float inter = iw * ih;
                float iou = inter / (ai + ar[j] - inter + 1e-9f);
                if (iou > NMS_T) m |= (1ull << tb);
            }
        }
        msk[t] = m;
    }
    __syncthreads();

    if (tid == 0) {
        keep[0] = keep[1] = keep[2] = keep[3] = keep[4] = ~0ull;
        for (int i = 0; i < KC; i++) {
            if ((keep[i >> 6] >> (i & 63)) & 1ull) {
#pragma unroll
                for (int w = 0; w < 5; w++) keep[w] &= ~msk[i * 5 + w];
            }
        }
        // output order: kept (score desc == index asc), then non-kept (index asc,
        // matching top_k tie-break among zeros)
        int c2 = 0;
        for (int i = 0; i < KC && c2 < DET; i++)
            if ((keep[i >> 6] >> (i & 63)) & 1ull) { order[c2] = i; okept[c2] = 1; c2++; }
        for (int i = 0; i < KC && c2 < DET; i++)
            if (!((keep[i >> 6] >> (i & 63)) & 1ull)) { order[c2] = i; okept[c2] = 0; c2++; }
    }
    __syncthreads();

    if (tid < DET) {
        int o = order[tid];
        float scale = scalef[b];
        float4 bb = bx[o];
        float s = (okept[tid] && o < valid) ? sc[o] : 0.f;
        float lb = (o < valid) ? (float)lab[o] : 0.f;
        float* po = out + ((size_t)b * DET + tid) * 6;
        po[0] = bb.x / scale;
        po[1] = bb.y / scale;
        po[2] = bb.z / scale;
        po[3] = bb.w / scale;
        po[4] = s;
        po[5] = lb;
    }
}

extern "C" void kernel_launch(void* const* d_in, const int* in_sizes, int n_in,
                              void* d_out, int out_size, void* d_ws, size_t ws_size,
                              hipStream_t stream) {
    const float* p3 = (const float*)d_in[0];
    const float* p4 = (const float*)d_in[1];
    const float* p5 = (const float*)d_in[2];
    const float* anchors = (const float*)d_in[3];
    const int* imshapes = (const int*)d_in[4];
    const float* scalef = (const float*)d_in[5];
    float* out = (float*)d_out;

    // workspace layout (re-poisoned every launch -> zero what we accumulate into)
    unsigned int* hist = (unsigned int*)d_ws;            // [16][256]
    unsigned int* cnt = hist + BATCH * NBINS;            // [16]
    int* binT = (int*)(cnt + BATCH);                     // [16]
    uint2* cand = (uint2*)(binT + BATCH);                // [16][CAP] (8B aligned)

    int zn = BATCH * NBINS + BATCH;  // hist + cnt contiguous
    k_zero<<<(zn + 255) / 256, 256, 0, stream>>>(hist, zn);

    const int BPI = (NANCH + 255) / 256;  // 99
    k_hist<<<BATCH * BPI, 256, 0, stream>>>(p3, p4, p5, hist);
    k_thresh<<<1, 64, 0, stream>>>(hist, binT);
    k_collect<<<BATCH * BPI, 256, 0, stream>>>(p3, p4, p5, binT, cnt, cand);
    k_final<<<BATCH, 512, 0, stream>>>(p3, p4, p5, anchors, imshapes, scalef, cnt, cand, out);
}

// Round 2
// 398.115 us; speedup vs baseline: 2.9007x; 2.9007x over previous
//
#include <hip/hip_runtime.h>
#include <cstdint>
#include <cstddef>

#define BATCH 16
#define NCLS 80
#define NANCH 25200          // (80*80 + 40*40 + 20*20) * 3
#define G 48                 // anchors per k_max block (divides 19200/4800/1200)
#define CHUNKS 525           // 400 + 100 + 25 chunks of 48 anchors
#define ABINS 512
#define SBINS 256
#define ACAP 1536
#define SCAP 2048            // bitonic sort size
#define KC 300
#define DET 100
#define SCORE_T 0.25f
#define NMS_T 0.45f

__device__ __forceinline__ float sg(float x) { return 1.0f / (1.0f + expf(-x)); }

__device__ __forceinline__ const float* anchor_base(const float* p3, const float* p4,
                                                    const float* p5, int b, int n) {
    if (n < 19200) return p3 + ((size_t)b * 19200 + n) * 85;
    if (n < 24000) return p4 + ((size_t)b * 4800 + (n - 19200)) * 85;
    return p5 + ((size_t)b * 1200 + (n - 24000)) * 85;
}

// Coalesced pass over all predictions: per-anchor max score (0 if obj<=T).
__global__ __launch_bounds__(256) void k_max(const float* __restrict__ p3,
                                             const float* __restrict__ p4,
                                             const float* __restrict__ p5,
                                             float* __restrict__ gmax) {
    __shared__ float buf[G * 85];      // 4080 floats = 16.3 KB, float4-aligned chunks
    __shared__ float pmax[5 * G];
    int b = blockIdx.x / CHUNKS;
    int ch = blockIdx.x % CHUNKS;
    const float* src; int a0, lvlN, gbase;
    if (ch < 400)      { src = p3; a0 = ch * G;         lvlN = 19200; gbase = 0; }
    else if (ch < 500) { src = p4; a0 = (ch - 400) * G; lvlN = 4800;  gbase = 19200; }
    else               { src = p5; a0 = (ch - 500) * G; lvlN = 1200;  gbase = 24000; }
    const float4* s4 = (const float4*)(src + ((size_t)b * lvlN + a0) * 85);
    for (int i = threadIdx.x; i < (G * 85) / 4; i += 256)
        ((float4*)buf)[i] = s4[i];
    __syncthreads();
    int tid = threadIdx.x;
    if (tid < 240) {                   // 48 anchors x 5 parts of 16 classes
        int a = tid % G, part = tid / G;
        const float* base = buf + a * 85;
        float obj = sg(base[4]);
        float m = 0.0f;
        if (obj > SCORE_T) {           // score = obj*cls < obj, so obj<=T => all scores <=T
            for (int k = 0; k < 16; k++)
                m = fmaxf(m, obj * sg(base[5 + part * 16 + k]));
        }
        pmax[part * G + a] = m;
    }
    __syncthreads();
    if (tid < G) {
        float m = pmax[tid];
        for (int p = 1; p < 5; p++) m = fmaxf(m, pmax[p * G + tid]);
        gmax[(size_t)b * NANCH + gbase + a0 + tid] = m;
    }
}

// Per-image: anchor selection, score selection, sort, decode, NMS, output [100,6]
__global__ __launch_bounds__(512) void k_final(
    const float* __restrict__ p3, const float* __restrict__ p4, const float* __restrict__ p5,
    const float* __restrict__ anchors, const int* __restrict__ imshapes,
    const float* __restrict__ scalef, const float* __restrict__ gmax,
    float* __restrict__ out) {
    __shared__ unsigned int hista[ABINS];
    __shared__ unsigned int shist[SBINS];
    __shared__ int alist[ACAP];
    __shared__ float aobj[ACAP];
    __shared__ float sv[SCAP];
    __shared__ unsigned int si[SCAP];
    __shared__ float4 bx[KC];
    __shared__ int lab[KC];
    __shared__ float sc[KC];
    __shared__ float ar[KC];
    __shared__ unsigned long long msk[KC * 5];
    __shared__ unsigned long long keep[5];
    __shared__ int order[DET];
    __shared__ int okept[DET];
    __shared__ unsigned int acnt, scnt;
    __shared__ int binTa, binTs;

    int b = blockIdx.x;
    int tid = threadIdx.x;

    for (int i = tid; i < ABINS; i += 512) hista[i] = 0u;
    for (int i = tid; i < SBINS; i += 512) shist[i] = 0u;
    if (tid == 0) { acnt = 0u; scnt = 0u; }
    __syncthreads();

    const float* gm = gmax + (size_t)b * NANCH;

    // ---- anchor-max histogram ----
    for (int n = tid; n < NANCH; n += 512) {
        float v = gm[n];
        if (v > SCORE_T) {
            int bin = (int)((v - SCORE_T) * (ABINS / 0.75f));
            bin = bin < 0 ? 0 : (bin > ABINS - 1 ? ABINS - 1 : bin);
            atomicAdd(&hista[bin], 1u);
        }
    }
    __syncthreads();
    if (tid == 0) {
        unsigned int cum = 0; int T = 0;
        for (int i = ABINS - 1; i >= 0; i--) { cum += hista[i]; if (cum >= KC) { T = i; break; } }
        binTa = T;
    }
    __syncthreads();
    int Ta = binTa;

    // ---- collect candidate anchors (superset of anchors holding top-300 scores) ----
    for (int n = tid; n < NANCH; n += 512) {
        float v = gm[n];
        if (v > SCORE_T) {
            int bin = (int)((v - SCORE_T) * (ABINS / 0.75f));
            bin = bin < 0 ? 0 : (bin > ABINS - 1 ? ABINS - 1 : bin);
            if (bin >= Ta) {
                unsigned int pos = atomicAdd(&acnt, 1u);
                if (pos < ACAP) alist[pos] = n;
            }
        }
    }
    __syncthreads();
    int M = (int)(acnt < ACAP ? acnt : ACAP);

    for (int i = tid; i < M; i += 512)
        aobj[i] = sg(anchor_base(p3, p4, p5, b, alist[i])[4]);
    __syncthreads();

    // ---- score histogram over candidate anchors ----
    for (int w = tid; w < M * NCLS; w += 512) {
        int a = w / NCLS, c = w % NCLS;
        const float* base = anchor_base(p3, p4, p5, b, alist[a]);
        float s = aobj[a] * sg(base[5 + c]);
        if (s > SCORE_T) {
            int bin = (int)((s - SCORE_T) * (SBINS / 0.75f));
            bin = bin < 0 ? 0 : (bin > SBINS - 1 ? SBINS - 1 : bin);
            atomicAdd(&shist[bin], 1u);
        }
    }
    __syncthreads();
    if (tid == 0) {
        unsigned int cum = 0; int T = 0;
        for (int i = SBINS - 1; i >= 0; i--) { cum += shist[i]; if (cum >= KC) { T = i; break; } }
        binTs = T;
    }
    __syncthreads();
    int Ts = binTs;

    // ---- collect (score, flat_idx) candidates ----
    for (int w = tid; w < M * NCLS; w += 512) {
        int a = w / NCLS, c = w % NCLS;
        const float* base = anchor_base(p3, p4, p5, b, alist[a]);
        float s = aobj[a] * sg(base[5 + c]);
        if (s > SCORE_T) {
            int bin = (int)((s - SCORE_T) * (SBINS / 0.75f));
            bin = bin < 0 ? 0 : (bin > SBINS - 1 ? SBINS - 1 : bin);
            if (bin >= Ts) {
                unsigned int pos = atomicAdd(&scnt, 1u);
                if (pos < SCAP) {
                    sv[pos] = s;
                    si[pos] = (unsigned int)(alist[a] * NCLS + c);
                }
            }
        }
    }
    __syncthreads();
    int nc = (int)(scnt < SCAP ? scnt : SCAP);
    for (int i = tid; i < SCAP; i += 512)
        if (i >= nc) { sv[i] = -1e30f; si[i] = 0xffffffffu; }
    __syncthreads();

    // ---- bitonic sort: score desc, flat-idx asc (jax top_k tie-break) ----
    for (int k = 2; k <= SCAP; k <<= 1) {
        for (int j = k >> 1; j > 0; j >>= 1) {
            for (int i = tid; i < SCAP; i += 512) {
                int ixj = i ^ j;
                if (ixj > i) {
                    float s1 = sv[i], s2 = sv[ixj];
                    unsigned int i1 = si[i], i2 = si[ixj];
                    bool pre = (s1 > s2) || (s1 == s2 && i1 < i2);
                    bool up = ((i & k) == 0);
                    if (pre != up) { sv[i] = s2; sv[ixj] = s1; si[i] = i2; si[ixj] = i1; }
                }
            }
            __syncthreads();
        }
    }

    // ---- decode top-300 boxes ----
    int valid = nc < KC ? nc : KC;
    if (tid < KC) {
        int i = tid;
        if (i < valid) {
            unsigned int fi = si[i];
            int n = (int)(fi / NCLS), c = (int)(fi % NCLS);
            int lvl = (n < 19200) ? 0 : (n < 24000 ? 1 : 2);
            const int offl[3] = {0, 19200, 24000};
            const int Wl[3] = {80, 40, 20};
            const int cntl[3] = {19200, 4800, 1200};
            const float strl[3] = {8.f, 16.f, 32.f};
            const float* pp = lvl == 0 ? p3 : (lvl == 1 ? p4 : p5);
            int nl = n - offl[lvl];
            int a = nl % 3, cell = nl / 3;
            int gx = cell % Wl[lvl], gy = cell / Wl[lvl];
            const float* pb = pp + ((size_t)b * cntl[lvl] + nl) * 85;
            float s0 = sg(pb[0]), s1 = sg(pb[1]), s2 = sg(pb[2]), s3 = sg(pb[3]);
            float stride = strl[lvl];
            float aw = anchors[(lvl * 3 + a) * 2 + 0];
            float ah = anchors[(lvl * 3 + a) * 2 + 1];
            float cx = (2.0f * s0 - 0.5f + (float)gx) * stride;
            float cy = (2.0f * s1 - 0.5f + (float)gy) * stride;
            float bw = 4.0f * s2 * s2 * aw;
            float bh = 4.0f * s3 * s3 * ah;
            float hf = (float)imshapes[b * 2 + 0];
            float wf = (float)imshapes[b * 2 + 1];
            float x1 = cx - bw / 2.0f, y1 = cy - bh / 2.0f;
            float x2 = cx + bw / 2.0f, y2 = cy + bh / 2.0f;
            x1 = fminf(fmaxf(x1, 0.f), wf);
            y1 = fminf(fmaxf(y1, 0.f), hf);
            x2 = fminf(fmaxf(x2, 0.f), wf);
            y2 = fminf(fmaxf(y2, 0.f), hf);
            bx[i] = make_float4(x1, y1, x2, y2);
            lab[i] = c;
            sc[i] = sv[i];
            ar[i] = (x2 - x1) * (y2 - y1);
        } else {
            bx[i] = make_float4(0, 0, 0, 0);
            lab[i] = -1 - i;   // unique: never matches in NMS
            sc[i] = 0.f;
            ar[i] = 0.f;
        }
    }
    __syncthreads();

    // ---- suppression bitmask (class-offset NMS == same-label plain IoU) ----
    for (int t = tid; t < KC * 5; t += 512) {
        int i = t / 5, w = t % 5;
        float4 bi = bx[i];
        int li = lab[i];
        float ai = ar[i];
        unsigned long long m = 0ull;
        for (int tb = 0; tb < 64; tb++) {
            int j = w * 64 + tb;
            if (j < KC && j > i && lab[j] == li) {
                float4 bj = bx[j];
                float ltx = fmaxf(bi.x, bj.x), lty = fmaxf(bi.y, bj.y);
                float rbx = fminf(bi.z, bj.z), rby = fminf(bi.w, bj.w);
                float iw = fmaxf(rbx - ltx, 0.f), ih = fmaxf(rby - lty, 0.f);
                float inter = iw * ih;
                float iou = inter / (ai + ar[j] - inter + 1e-9f);
                if (iou > NMS_T) m |= (1ull << tb);
            }
        }
        msk[t] = m;
    }
    __syncthreads();

    if (tid == 0) {
        keep[0] = keep[1] = keep[2] = keep[3] = keep[4] = ~0ull;
        for (int i = 0; i < KC; i++) {
            if ((keep[i >> 6] >> (i & 63)) & 1ull) {
#pragma unroll
                for (int w = 0; w < 5; w++) keep[w] &= ~msk[i * 5 + w];
            }
        }
        int c2 = 0;
        for (int i = 0; i < KC && c2 < DET; i++)
            if ((keep[i >> 6] >> (i & 63)) & 1ull) { order[c2] = i; okept[c2] = 1; c2++; }
        for (int i = 0; i < KC && c2 < DET; i++)
            if (!((keep[i >> 6] >> (i & 63)) & 1ull)) { order[c2] = i; okept[c2] = 0; c2++; }
    }
    __syncthreads();

    if (tid < DET) {
        int o = order[tid];
        float scale = scalef[b];
        float4 bb = bx[o];
        float s = (okept[tid] && o < valid) ? sc[o] : 0.f;
        float lb = (o < valid) ? (float)lab[o] : 0.f;
        float* po = out + ((size_t)b * DET + tid) * 6;
        po[0] = bb.x / scale;
        po[1] = bb.y / scale;
        po[2] = bb.z / scale;
        po[3] = bb.w / scale;
        po[4] = s;
        po[5] = lb;
    }
}

extern "C" void kernel_launch(void* const* d_in, const int* in_sizes, int n_in,
                              void* d_out, int out_size, void* d_ws, size_t ws_size,
                              hipStream_t stream) {
    const float* p3 = (const float*)d_in[0];
    const float* p4 = (const float*)d_in[1];
    const float* p5 = (const float*)d_in[2];
    const float* anchors = (const float*)d_in[3];
    const int* imshapes = (const int*)d_in[4];
    const float* scalef = (const float*)d_in[5];
    float* out = (float*)d_out;

    float* gmax = (float*)d_ws;   // [16][25200] floats = 1.6 MB, fully written by k_max

    k_max<<<BATCH * CHUNKS, 256, 0, stream>>>(p3, p4, p5, gmax);
    k_final<<<BATCH, 512, 0, stream>>>(p3, p4, p5, anchors, imshapes, scalef, gmax, out);
}

// Round 4
// 352.092 us; speedup vs baseline: 3.2798x; 1.1307x over previous
//
#include <hip/hip_runtime.h>
#include <cstdint>
#include <cstddef>

#define BATCH 16
#define NCLS 80
#define NANCH 25200          // (80*80 + 40*40 + 20*20) * 3
#define G 48                 // anchors per chunk
#define NCHUNK 525           // chunks per image (400 + 100 + 25)
#define TOTCH (BATCH * NCHUNK)   // 8400
#define CPB 4                // chunks per k_max block
#define ABINS 512
#define SBINS 1024
#define ACAP 2048
#define SCAP 2048
#define KC 300
#define DET 100
#define SCORE_T 0.25f
#define NMS_T 0.45f

__device__ __forceinline__ float sg(float x) { return 1.0f / (1.0f + expf(-x)); }

__device__ __forceinline__ const float* anchor_base(const float* p3, const float* p4,
                                                    const float* p5, int b, int n) {
    if (n < 19200) return p3 + ((size_t)b * 19200 + n) * 85;
    if (n < 24000) return p4 + ((size_t)b * 4800 + (n - 19200)) * 85;
    return p5 + ((size_t)b * 1200 + (n - 24000)) * 85;
}

struct Chunk { const float4* p; int b; int outbase; };
__device__ __forceinline__ Chunk chunk_of(int g, const float* p3, const float* p4,
                                          const float* p5) {
    Chunk ck;
    int b = g / NCHUNK, ch = g % NCHUNK;
    const float* src; int a0, lvlN, gbase;
    if (ch < 400)      { src = p3; a0 = ch * G;         lvlN = 19200; gbase = 0; }
    else if (ch < 500) { src = p4; a0 = (ch - 400) * G; lvlN = 4800;  gbase = 19200; }
    else               { src = p5; a0 = (ch - 500) * G; lvlN = 1200;  gbase = 24000; }
    ck.p = (const float4*)(src + ((size_t)b * lvlN + a0) * 85);
    ck.b = b;
    ck.outbase = b * NANCH + gbase + a0;
    return ck;
}

__global__ void k_zero(unsigned int* w, int n) {
    int i = blockIdx.x * blockDim.x + threadIdx.x;
    if (i < n) w[i] = 0u;
}

// Streaming pass: per-anchor max score via sigma(obj)*sigma(max logit)
// (sigma is float-monotone => equals max over classes of sigma(obj)*sigma(cls)).
// Also builds per-image anchor histogram.
__global__ __launch_bounds__(256) void k_max(const float* __restrict__ p3,
                                             const float* __restrict__ p4,
                                             const float* __restrict__ p5,
                                             float* __restrict__ gmax,
                                             unsigned int* __restrict__ hista) {
    __shared__ __align__(16) float buf[G * 85];   // 16320 B
    __shared__ float pmax[5 * G];
    int tid = threadIdx.x;
    int g0 = blockIdx.x * CPB;
    Chunk cur = chunk_of(g0, p3, p4, p5);
    float4 pre[4];
#pragma unroll
    for (int r = 0; r < 4; r++) {
        int i = tid + r * 256;
        pre[r] = (i < (G * 85 / 4)) ? cur.p[i] : make_float4(0.f, 0.f, 0.f, 0.f);
    }
    for (int it = 0; it < CPB; ++it) {
        // store current chunk's prefetched regs -> LDS
#pragma unroll
        for (int r = 0; r < 4; r++) {
            int i = tid + r * 256;
            if (i < (G * 85 / 4)) ((float4*)buf)[i] = pre[r];
        }
        // issue next chunk's loads (overlap with compute below)
        Chunk nxt = cur;
        if (it + 1 < CPB) {
            nxt = chunk_of(g0 + it + 1, p3, p4, p5);
#pragma unroll
            for (int r = 0; r < 4; r++) {
                int i = tid + r * 256;
                pre[r] = (i < (G * 85 / 4)) ? nxt.p[i] : make_float4(0.f, 0.f, 0.f, 0.f);
            }
        }
        __syncthreads();
        // raw-logit max over classes: 48 anchors x 5 parts of 16
        if (tid < 240) {
            int a = tid % G, part = tid / G;
            const float* base = buf + a * 85 + 5 + part * 16;
            float m = base[0];
#pragma unroll
            for (int k = 1; k < 16; k++) m = fmaxf(m, base[k]);
            pmax[part * G + a] = m;
        }
        __syncthreads();
        if (tid < G) {
            float m = pmax[tid];
#pragma unroll
            for (int p = 1; p < 5; p++) m = fmaxf(m, pmax[p * G + tid]);
            float obj = sg(buf[tid * 85 + 4]);
            float v = 0.0f;
            if (obj > SCORE_T) v = obj * sg(m);
            gmax[cur.outbase + tid] = v;
            if (v > SCORE_T) {
                int bin = (int)((v - SCORE_T) * (ABINS / 0.75f));
                bin = bin < 0 ? 0 : (bin > ABINS - 1 ? ABINS - 1 : bin);
                atomicAdd(&hista[cur.b * ABINS + bin], 1u);
            }
        }
        __syncthreads();   // protect buf before next iteration's store
        cur = nxt;
    }
}

// Parallel suffix-scan threshold: largest bin T with suffix-count >= KC.
__global__ __launch_bounds__(1024) void k_thresh(const unsigned int* __restrict__ hist,
                                                 int bins, int* __restrict__ binT) {
    __shared__ unsigned int ssum[SBINS];
    int b = blockIdx.x, t = threadIdx.x;
    unsigned int run = hist[b * bins + t];
    ssum[t] = run;
    __syncthreads();
    for (int off = 1; off < bins; off <<= 1) {
        unsigned int add = (t + off < bins) ? ssum[t + off] : 0u;
        __syncthreads();
        run += add;
        ssum[t] = run;
        __syncthreads();
    }
    if (run >= KC && (t == bins - 1 || ssum[t + 1] < KC)) binT[b] = t;
    if (t == 0 && run < KC) binT[b] = 0;
}

__global__ void k_collectA(const float* __restrict__ gmax, const int* __restrict__ binTa,
                           unsigned int* __restrict__ acnt, int* __restrict__ alist) {
    int b = blockIdx.x / 99;
    int n = (blockIdx.x % 99) * 256 + threadIdx.x;
    if (n >= NANCH) return;
    float v = gmax[b * NANCH + n];
    if (v > SCORE_T) {
        int bin = (int)((v - SCORE_T) * (ABINS / 0.75f));
        bin = bin < 0 ? 0 : (bin > ABINS - 1 ? ABINS - 1 : bin);
        if (bin >= binTa[b]) {
            unsigned int pos = atomicAdd(&acnt[b], 1u);
            if (pos < ACAP) alist[b * ACAP + pos] = n;
        }
    }
}

// Score histogram over candidate anchors (parallel across chip).
__global__ __launch_bounds__(256) void k_score(const float* __restrict__ p3,
                                               const float* __restrict__ p4,
                                               const float* __restrict__ p5,
                                               const unsigned int* __restrict__ acnt,
                                               const int* __restrict__ alist,
                                               unsigned int* __restrict__ shist) {
    __shared__ unsigned int lh[SBINS];
    int b = blockIdx.x / 16, sub = blockIdx.x % 16;
    for (int i = threadIdx.x; i < SBINS; i += 256) lh[i] = 0u;
    __syncthreads();
    int M = (int)acnt[b]; if (M > ACAP) M = ACAP;
    int tot = M * NCLS;
    for (int w = sub * 256 + threadIdx.x; w < tot; w += 16 * 256) {
        int n = alist[b * ACAP + w / NCLS], c = w % NCLS;
        const float* base = anchor_base(p3, p4, p5, b, n);
        float s = sg(base[4]) * sg(base[5 + c]);
        if (s > SCORE_T) {
            int bin = (int)((s - SCORE_T) * (SBINS / 0.75f));
            bin = bin < 0 ? 0 : (bin > SBINS - 1 ? SBINS - 1 : bin);
            atomicAdd(&lh[bin], 1u);
        }
    }
    __syncthreads();
    for (int i = threadIdx.x; i < SBINS; i += 256) {
        unsigned int v = lh[i];
        if (v) atomicAdd(&shist[b * SBINS + i], v);
    }
}

__global__ __launch_bounds__(256) void k_collectS(const float* __restrict__ p3,
                                                  const float* __restrict__ p4,
                                                  const float* __restrict__ p5,
                                                  const unsigned int* __restrict__ acnt,
                                                  const int* __restrict__ alist,
                                                  const int* __restrict__ binTs,
                                                  unsigned int* __restrict__ scnt,
                                                  uint2* __restrict__ cand) {
    int b = blockIdx.x / 16, sub = blockIdx.x % 16;
    int M = (int)acnt[b]; if (M > ACAP) M = ACAP;
    int tot = M * NCLS;
    int Ts = binTs[b];
    for (int w = sub * 256 + threadIdx.x; w < tot; w += 16 * 256) {
        int n = alist[b * ACAP + w / NCLS], c = w % NCLS;
        const float* base = anchor_base(p3, p4, p5, b, n);
        float s = sg(base[4]) * sg(base[5 + c]);   // identical expression to k_score
        if (s > SCORE_T) {
            int bin = (int)((s - SCORE_T) * (SBINS / 0.75f));
            bin = bin < 0 ? 0 : (bin > SBINS - 1 ? SBINS - 1 : bin);
            if (bin >= Ts) {
                unsigned int pos = atomicAdd(&scnt[b], 1u);
                if (pos < SCAP)
                    cand[(size_t)b * SCAP + pos] =
                        make_uint2(__float_as_uint(s), (unsigned int)(n * NCLS + c));
            }
        }
    }
}

// Per-image: dynamic bitonic sort, decode top-300, NMS (wave-parallel), output [100,6]
__global__ __launch_bounds__(512) void k_final(
    const float* __restrict__ p3, const float* __restrict__ p4, const float* __restrict__ p5,
    const float* __restrict__ anchors, const int* __restrict__ imshapes,
    const float* __restrict__ scalef, const unsigned int* __restrict__ scnt,
    const uint2* __restrict__ cand, float* __restrict__ out) {
    __shared__ float sv[SCAP];
    __shared__ unsigned int si[SCAP];
    __shared__ float4 bx[KC];
    __shared__ int lab[KC];
    __shared__ float sc[KC];
    __shared__ float ar[KC];
    __shared__ unsigned long long msk[KC * 5];
    __shared__ unsigned long long keep[5];
    __shared__ int wpref[6];
    __shared__ int order[DET];
    __shared__ int okept[DET];

    int b = blockIdx.x;
    int tid = threadIdx.x;
    int nc = (int)scnt[b];
    if (nc > SCAP) nc = SCAP;
    int nsort = 64;
    while (nsort < nc) nsort <<= 1;

    for (int i = tid; i < nsort; i += 512) {
        if (i < nc) {
            uint2 cc = cand[(size_t)b * SCAP + i];
            sv[i] = __uint_as_float(cc.x);
            si[i] = cc.y;
        } else {
            sv[i] = -1e30f;
            si[i] = 0xffffffffu;
        }
    }
    __syncthreads();

    // bitonic sort over nsort: score desc, flat-idx asc (jax top_k tie-break)
    for (int k = 2; k <= nsort; k <<= 1) {
        for (int j = k >> 1; j > 0; j >>= 1) {
            for (int i = tid; i < nsort; i += 512) {
                int ixj = i ^ j;
                if (ixj > i) {
                    float s1 = sv[i], s2 = sv[ixj];
                    unsigned int i1 = si[i], i2 = si[ixj];
                    bool pre = (s1 > s2) || (s1 == s2 && i1 < i2);
                    bool up = ((i & k) == 0);
                    if (pre != up) { sv[i] = s2; sv[ixj] = s1; si[i] = i2; si[ixj] = i1; }
                }
            }
            __syncthreads();
        }
    }

    // decode top-300 boxes
    int valid = nc < KC ? nc : KC;
    if (tid < KC) {
        int i = tid;
        if (i < valid) {
            unsigned int fi = si[i];
            int n = (int)(fi / NCLS), c = (int)(fi % NCLS);
            int lvl = (n < 19200) ? 0 : (n < 24000 ? 1 : 2);
            const int offl[3] = {0, 19200, 24000};
            const int Wl[3] = {80, 40, 20};
            const int cntl[3] = {19200, 4800, 1200};
            const float strl[3] = {8.f, 16.f, 32.f};
            const float* pp = lvl == 0 ? p3 : (lvl == 1 ? p4 : p5);
            int nl = n - offl[lvl];
            int a = nl % 3, cell = nl / 3;
            int gx = cell % Wl[lvl], gy = cell / Wl[lvl];
            const float* pb = pp + ((size_t)b * cntl[lvl] + nl) * 85;
            float s0 = sg(pb[0]), s1 = sg(pb[1]), s2 = sg(pb[2]), s3 = sg(pb[3]);
            float stride = strl[lvl];
            float aw = anchors[(lvl * 3 + a) * 2 + 0];
            float ah = anchors[(lvl * 3 + a) * 2 + 1];
            float cx = (2.0f * s0 - 0.5f + (float)gx) * stride;
            float cy = (2.0f * s1 - 0.5f + (float)gy) * stride;
            float bw = 4.0f * s2 * s2 * aw;
            float bh = 4.0f * s3 * s3 * ah;
            float hf = (float)imshapes[b * 2 + 0];
            float wf = (float)imshapes[b * 2 + 1];
            float x1 = cx - bw / 2.0f, y1 = cy - bh / 2.0f;
            float x2 = cx + bw / 2.0f, y2 = cy + bh / 2.0f;
            x1 = fminf(fmaxf(x1, 0.f), wf);
            y1 = fminf(fmaxf(y1, 0.f), hf);
            x2 = fminf(fmaxf(x2, 0.f), wf);
            y2 = fminf(fmaxf(y2, 0.f), hf);
            bx[i] = make_float4(x1, y1, x2, y2);
            lab[i] = c;
            sc[i] = sv[i];
            ar[i] = (x2 - x1) * (y2 - y1);
        } else {
            bx[i] = make_float4(0, 0, 0, 0);
            lab[i] = -1 - i;   // unique: never matches in NMS
            sc[i] = 0.f;
            ar[i] = 0.f;
        }
    }
    __syncthreads();

    // suppression bitmask rows (class-offset NMS == same-label plain IoU)
    for (int t = tid; t < KC * 5; t += 512) {
        int i = t / 5, w = t % 5;
        float4 bi = bx[i];
        int li = lab[i];
        float ai = ar[i];
        unsigned long long m = 0ull;
        for (int tb = 0; tb < 64; tb++) {
            int j = w * 64 + tb;
            if (j < KC && j > i && lab[j] == li) {
                float4 bj = bx[j];
                float ltx = fmaxf(bi.x, bj.x), lty = fmaxf(bi.y, bj.y);
                float rbx = fminf(bi.z, bj.z), rby = fminf(bi.w, bj.w);
                float iw = fmaxf(rbx - ltx, 0.f), ih = fmaxf(rby - lty, 0.f);
                float inter = iw * ih;
                float iou = inter / (ai + ar[j] - inter + 1e-9f);
                if (iou > NMS_T) m |= (1ull << tb);
            }
        }
        msk[t] = m;
    }
    __syncthreads();

    // wave-parallel greedy NMS scan: lanes 0..4 own keep words, shfl-broadcast bit
    if (tid < 64) {
        unsigned long long kw = ~0ull;
        unsigned long long nrow = (tid < 5) ? msk[tid] : 0ull;
        for (int i = 0; i < KC; i++) {
            unsigned long long row = nrow;
            nrow = (tid < 5 && i + 1 < KC) ? msk[(i + 1) * 5 + tid] : 0ull;
            unsigned long long kwi = __shfl(kw, i >> 6);
            if (((kwi >> (i & 63)) & 1ull) && tid < 5) kw &= ~row;
        }
        if (tid < 5) keep[tid] = kw;
    }
    __syncthreads();

    // rank kept (index asc == score desc) then non-kept (index asc) via popcounts
    if (tid == 0) {
        int s = 0;
        for (int w = 0; w < 5; w++) {
            unsigned long long kw = keep[w];
            if (w == 4) kw &= (1ull << 44) - 1ull;   // bits >= KC excluded
            wpref[w] = s;
            s += (int)__popcll(kw);
        }
        wpref[5] = s;
    }
    __syncthreads();
    if (tid < KC) {
        int w = tid >> 6, bp = tid & 63;
        unsigned long long kw = keep[w];
        bool kept = (kw >> bp) & 1ull;
        int r = wpref[w] + (int)__popcll(kw & ((1ull << bp) - 1ull));
        if (kept) {
            if (r < DET) { order[r] = tid; okept[r] = 1; }
        } else {
            int nr = wpref[5] + (tid - r);
            if (nr < DET) { order[nr] = tid; okept[nr] = 0; }
        }
    }
    __syncthreads();

    if (tid < DET) {
        int o = order[tid];
        float scale = scalef[b];
        float4 bb = bx[o];
        float s = (okept[tid] && o < valid) ? sc[o] : 0.f;
        float lb = (o < valid) ? (float)lab[o] : 0.f;
        float* po = out + ((size_t)b * DET + tid) * 6;
        po[0] = bb.x / scale;
        po[1] = bb.y / scale;
        po[2] = bb.z / scale;
        po[3] = bb.w / scale;
        po[4] = s;
        po[5] = lb;
    }
}

extern "C" void kernel_launch(void* const* d_in, const int* in_sizes, int n_in,
                              void* d_out, int out_size, void* d_ws, size_t ws_size,
                              hipStream_t stream) {
    const float* p3 = (const float*)d_in[0];
    const float* p4 = (const float*)d_in[1];
    const float* p5 = (const float*)d_in[2];
    const float* anchors = (const float*)d_in[3];
    const int* imshapes = (const int*)d_in[4];
    const float* scalef = (const float*)d_in[5];
    float* out = (float*)d_out;

    // workspace layout (words)
    float* gmax = (float*)d_ws;                               // 16*25200
    unsigned int* hista = (unsigned int*)(gmax + BATCH * NANCH);  // 16*512
    unsigned int* shist = hista + BATCH * ABINS;              // 16*1024
    unsigned int* acnt = shist + BATCH * SBINS;               // 16
    unsigned int* scnt = acnt + BATCH;                        // 16
    int* binTa = (int*)(scnt + BATCH);                        // 16
    int* binTs = binTa + BATCH;                               // 16
    int* alist = binTs + BATCH;                               // 16*2048
    uint2* cand = (uint2*)(alist + BATCH * ACAP);             // 16*2048 uint2 (8B aligned)

    int zn = BATCH * ABINS + BATCH * SBINS + 2 * BATCH;   // hista+shist+acnt+scnt contiguous
    k_zero<<<(zn + 255) / 256, 256, 0, stream>>>(hista, zn);

    k_max<<<TOTCH / CPB, 256, 0, stream>>>(p3, p4, p5, gmax, hista);
    k_thresh<<<BATCH, ABINS, 0, stream>>>(hista, ABINS, binTa);
    k_collectA<<<BATCH * 99, 256, 0, stream>>>(gmax, binTa, acnt, alist);
    k_score<<<BATCH * 16, 256, 0, stream>>>(p3, p4, p5, acnt, alist, shist);
    k_thresh<<<BATCH, SBINS, 0, stream>>>(shist, SBINS, binTs);
    k_collectS<<<BATCH * 16, 256, 0, stream>>>(p3, p4, p5, acnt, alist, binTs, scnt, cand);
    k_final<<<BATCH, 512, 0, stream>>>(p3, p4, p5, anchors, imshapes, scalef, scnt, cand, out);
}

// Round 6
// 271.555 us; speedup vs baseline: 4.2525x; 1.2966x over previous
//
#include <hip/hip_runtime.h>
#include <cstdint>
#include <cstddef>

#define BATCH 16
#define NCLS 80
#define NANCH 25200          // (80*80 + 40*40 + 20*20) * 3
#define G 48                 // anchors per chunk
#define NCHUNK 525           // chunks per image (400 + 100 + 25)
#define TOTCH (BATCH * NCHUNK)   // 8400
#define CPB 4                // chunks per k_max block
#define ABINS 512
#define SBINS 1024
#define ACAP 2048
#define SCAP 2048
#define TILE 64              // anchors staged per LDS tile in k_img
#define KC 300
#define DET 100
#define SCORE_T 0.25f
#define NMS_T 0.45f

__device__ __forceinline__ float sg(float x) { return 1.0f / (1.0f + expf(-x)); }

__device__ __forceinline__ const float* anchor_base(const float* p3, const float* p4,
                                                    const float* p5, int b, int n) {
    if (n < 19200) return p3 + ((size_t)b * 19200 + n) * 85;
    if (n < 24000) return p4 + ((size_t)b * 4800 + (n - 19200)) * 85;
    return p5 + ((size_t)b * 1200 + (n - 24000)) * 85;
}

struct Chunk { const float4* p; int outbase; };
__device__ __forceinline__ Chunk chunk_of(int g, const float* p3, const float* p4,
                                          const float* p5) {
    Chunk ck;
    int b = g / NCHUNK, ch = g % NCHUNK;
    const float* src; int a0, lvlN, gbase;
    if (ch < 400)      { src = p3; a0 = ch * G;         lvlN = 19200; gbase = 0; }
    else if (ch < 500) { src = p4; a0 = (ch - 400) * G; lvlN = 4800;  gbase = 19200; }
    else               { src = p5; a0 = (ch - 500) * G; lvlN = 1200;  gbase = 24000; }
    ck.p = (const float4*)(src + ((size_t)b * lvlN + a0) * 85);
    ck.outbase = b * NANCH + gbase + a0;
    return ck;
}

// Streaming pass: per-anchor max score via sigma(obj)*sigma(max logit)
// (sigma float-monotone => equals max over classes of sigma(obj)*sigma(cls)).
__global__ __launch_bounds__(256) void k_max(const float* __restrict__ p3,
                                             const float* __restrict__ p4,
                                             const float* __restrict__ p5,
                                             float* __restrict__ gmax) {
    __shared__ __align__(16) float buf[G * 85];   // 16320 B
    __shared__ float pmax[5 * G];
    int tid = threadIdx.x;
    int g0 = blockIdx.x * CPB;
    Chunk cur = chunk_of(g0, p3, p4, p5);
    float4 pre[4];
#pragma unroll
    for (int r = 0; r < 4; r++) {
        int i = tid + r * 256;
        pre[r] = (i < (G * 85 / 4)) ? cur.p[i] : make_float4(0.f, 0.f, 0.f, 0.f);
    }
    for (int it = 0; it < CPB; ++it) {
#pragma unroll
        for (int r = 0; r < 4; r++) {
            int i = tid + r * 256;
            if (i < (G * 85 / 4)) ((float4*)buf)[i] = pre[r];
        }
        Chunk nxt = cur;
        if (it + 1 < CPB) {
            nxt = chunk_of(g0 + it + 1, p3, p4, p5);
#pragma unroll
            for (int r = 0; r < 4; r++) {
                int i = tid + r * 256;
                pre[r] = (i < (G * 85 / 4)) ? nxt.p[i] : make_float4(0.f, 0.f, 0.f, 0.f);
            }
        }
        __syncthreads();
        if (tid < 240) {                   // 48 anchors x 5 parts of 16 classes
            int a = tid % G, part = tid / G;
            const float* base = buf + a * 85 + 5 + part * 16;
            float m = base[0];
#pragma unroll
            for (int k = 1; k < 16; k++) m = fmaxf(m, base[k]);
            pmax[part * G + a] = m;
        }
        __syncthreads();
        if (tid < G) {
            float m = pmax[tid];
#pragma unroll
            for (int p = 1; p < 5; p++) m = fmaxf(m, pmax[p * G + tid]);
            float obj = sg(buf[tid * 85 + 4]);
            float v = 0.0f;
            if (obj > SCORE_T) v = obj * sg(m);
            gmax[cur.outbase + tid] = v;
        }
        __syncthreads();
        cur = nxt;
    }
}

// Phase-overlay union: staging tile (passes C,E) vs NMS-phase arrays (G..end).
// These lifetimes never overlap.
union Ovl {
    struct { float tile[TILE * 85]; } p1;                 // 21760 B
    struct {
        unsigned long long msk[KC * 5];                   // 12000 B
        float4 bx[KC];
        int lab[KC];
        float sc2[KC];
        float ar[KC];
        unsigned long long keep[5];
        unsigned int actw[10];
        int wpref[6];
        int order[DET];
        int okept[DET];
    } p2;                                                 // ~21304 B
};

// Per-image mega-kernel: thresholds, candidate scoring, rank-select top-300,
// decode, NMS, output [100,6].  Static LDS ~52 KB.
__global__ __launch_bounds__(1024) void k_img(
    const float* __restrict__ p3, const float* __restrict__ p4, const float* __restrict__ p5,
    const float* __restrict__ anchors, const int* __restrict__ imshapes,
    const float* __restrict__ scalef, const float* __restrict__ gmax,
    float* __restrict__ out) {
    __shared__ unsigned int hist[SBINS];             // 4 KB
    __shared__ int alist[ACAP];                      // 8 KB
    __shared__ __align__(16) Ovl u;                  // 21.8 KB
    __shared__ float cs[SCAP];                       // 8 KB
    __shared__ unsigned int ci[SCAP];                // 8 KB
    __shared__ float sv[KC];
    __shared__ unsigned int si[KC];
    __shared__ unsigned int acnt, scnt;
    __shared__ int TaS, TsS;

    int b = blockIdx.x;
    int tid = threadIdx.x;
    const float* gm = gmax + (size_t)b * NANCH;

    // ---- A: anchor-max histogram (512 bins) ----
    hist[tid & (SBINS - 1)] = 0u;   // blockDim == SBINS
    if (tid == 0) { acnt = 0u; scnt = 0u; TaS = 0; TsS = 0; }
    __syncthreads();
    for (int n = tid; n < NANCH; n += 1024) {
        float v = gm[n];
        if (v > SCORE_T) {
            int bin = (int)((v - SCORE_T) * (ABINS / 0.75f));
            bin = bin < 0 ? 0 : (bin > ABINS - 1 ? ABINS - 1 : bin);
            atomicAdd(&hist[bin], 1u);
        }
    }
    __syncthreads();
    // suffix scan over 512 bins
    unsigned int run = 0;
    if (tid < ABINS) run = hist[tid];
    __syncthreads();
    for (int off = 1; off < ABINS; off <<= 1) {
        unsigned int add = (tid < ABINS && tid + off < ABINS) ? hist[tid + off] : 0u;
        __syncthreads();
        if (tid < ABINS) { run += add; hist[tid] = run; }
        __syncthreads();
    }
    if (tid < ABINS && run >= KC && (tid == ABINS - 1 || hist[tid + 1] < KC)) TaS = tid;
    __syncthreads();
    int Ta = TaS;

    // ---- B: collect candidate anchors ----
    for (int n = tid; n < NANCH; n += 1024) {
        float v = gm[n];
        if (v > SCORE_T) {
            int bin = (int)((v - SCORE_T) * (ABINS / 0.75f));
            bin = bin < 0 ? 0 : (bin > ABINS - 1 ? ABINS - 1 : bin);
            if (bin >= Ta) {
                unsigned int pos = atomicAdd(&acnt, 1u);
                if (pos < ACAP) alist[pos] = n;
            }
        }
    }
    __syncthreads();
    int M = (int)(acnt < ACAP ? acnt : ACAP);

    // ---- C: score histogram via staged tiles ----
    hist[tid] = 0u;
    __syncthreads();
    for (int t0 = 0; t0 < M; t0 += TILE) {
        int tc = min(TILE, M - t0);
        for (int idx = tid; idx < tc * 85; idx += 1024) {
            int a = idx / 85, f = idx - a * 85;
            u.p1.tile[idx] = anchor_base(p3, p4, p5, b, alist[t0 + a])[f];
        }
        __syncthreads();
        for (int idx = tid; idx < tc * 80; idx += 1024) {
            int a = idx / 80, c = idx - a * 80;
            float s = sg(u.p1.tile[a * 85 + 4]) * sg(u.p1.tile[a * 85 + 5 + c]);
            if (s > SCORE_T) {
                int bin = (int)((s - SCORE_T) * (SBINS / 0.75f));
                bin = bin < 0 ? 0 : (bin > SBINS - 1 ? SBINS - 1 : bin);
                atomicAdd(&hist[bin], 1u);
            }
        }
        __syncthreads();
    }
    // suffix scan over 1024 bins
    run = hist[tid];
    __syncthreads();
    for (int off = 1; off < SBINS; off <<= 1) {
        unsigned int add = (tid + off < SBINS) ? hist[tid + off] : 0u;
        __syncthreads();
        run += add;
        hist[tid] = run;
        __syncthreads();
    }
    if (run >= KC && (tid == SBINS - 1 || hist[tid + 1] < KC)) TsS = tid;
    __syncthreads();
    int Ts = TsS;

    // ---- E: collect (score, flat_idx) candidates (restage tiles) ----
    for (int t0 = 0; t0 < M; t0 += TILE) {
        int tc = min(TILE, M - t0);
        for (int idx = tid; idx < tc * 85; idx += 1024) {
            int a = idx / 85, f = idx - a * 85;
            u.p1.tile[idx] = anchor_base(p3, p4, p5, b, alist[t0 + a])[f];
        }
        __syncthreads();
        for (int idx = tid; idx < tc * 80; idx += 1024) {
            int a = idx / 80, c = idx - a * 80;
            float s = sg(u.p1.tile[a * 85 + 4]) * sg(u.p1.tile[a * 85 + 5 + c]);  // same expr as C
            if (s > SCORE_T) {
                int bin = (int)((s - SCORE_T) * (SBINS / 0.75f));
                bin = bin < 0 ? 0 : (bin > SBINS - 1 ? SBINS - 1 : bin);
                if (bin >= Ts) {
                    unsigned int pos = atomicAdd(&scnt, 1u);
                    if (pos < SCAP) {
                        cs[pos] = s;
                        ci[pos] = (unsigned int)(alist[t0 + a] * NCLS + c);
                    }
                }
            }
        }
        __syncthreads();
    }
    int nc = (int)(scnt < SCAP ? scnt : SCAP);

    // ---- F: rank-selection of top-300 (exact jax top_k order: score desc, idx asc) ----
    if (tid < KC) { sv[tid] = 0.f; si[tid] = 0xffffffffu; }
    __syncthreads();
    for (int i = tid; i < nc; i += 1024) {
        float s = cs[i];
        unsigned int ii = ci[i];
        int r = 0;
        for (int j = 0; j < nc; j++) {
            float sj = cs[j];
            unsigned int ij = ci[j];
            if (sj > s || (sj == s && ij < ii)) r++;
        }
        if (r < KC) { sv[r] = s; si[r] = ii; }
    }
    __syncthreads();
    int valid = nc < KC ? nc : KC;

    // ---- G: decode top-300 boxes (tile dead from here; overlay p2 live) ----
    if (tid < KC) {
        int i = tid;
        if (i < valid) {
            unsigned int fi = si[i];
            int n = (int)(fi / NCLS), c = (int)(fi % NCLS);
            int lvl = (n < 19200) ? 0 : (n < 24000 ? 1 : 2);
            const int offl[3] = {0, 19200, 24000};
            const int Wl[3] = {80, 40, 20};
            const int cntl[3] = {19200, 4800, 1200};
            const float strl[3] = {8.f, 16.f, 32.f};
            const float* pp = lvl == 0 ? p3 : (lvl == 1 ? p4 : p5);
            int nl = n - offl[lvl];
            int a = nl % 3, cell = nl / 3;
            int gx = cell % Wl[lvl], gy = cell / Wl[lvl];
            const float* pb = pp + ((size_t)b * cntl[lvl] + nl) * 85;
            float s0 = sg(pb[0]), s1 = sg(pb[1]), s2 = sg(pb[2]), s3 = sg(pb[3]);
            float stride = strl[lvl];
            float aw = anchors[(lvl * 3 + a) * 2 + 0];
            float ah = anchors[(lvl * 3 + a) * 2 + 1];
            float cx = (2.0f * s0 - 0.5f + (float)gx) * stride;
            float cy = (2.0f * s1 - 0.5f + (float)gy) * stride;
            float bw = 4.0f * s2 * s2 * aw;
            float bh = 4.0f * s3 * s3 * ah;
            float hf = (float)imshapes[b * 2 + 0];
            float wf = (float)imshapes[b * 2 + 1];
            float x1 = cx - bw / 2.0f, y1 = cy - bh / 2.0f;
            float x2 = cx + bw / 2.0f, y2 = cy + bh / 2.0f;
            x1 = fminf(fmaxf(x1, 0.f), wf);
            y1 = fminf(fmaxf(y1, 0.f), hf);
            x2 = fminf(fmaxf(x2, 0.f), wf);
            y2 = fminf(fmaxf(y2, 0.f), hf);
            u.p2.bx[i] = make_float4(x1, y1, x2, y2);
            u.p2.lab[i] = c;
            u.p2.sc2[i] = sv[i];
            u.p2.ar[i] = (x2 - x1) * (y2 - y1);
        } else {
            u.p2.bx[i] = make_float4(0, 0, 0, 0);
            u.p2.lab[i] = -1 - i;   // unique: never matches in NMS
            u.p2.sc2[i] = 0.f;
            u.p2.ar[i] = 0.f;
        }
    }
    __syncthreads();

    // ---- H: suppression bitmask rows (class-offset NMS == same-label plain IoU) ----
    if (tid < 10) u.p2.actw[tid] = 0u;   // zero here (overlay was tile earlier)
    for (int t = tid; t < KC * 5; t += 1024) {
        int i = t / 5, w = t % 5;
        float4 bi = u.p2.bx[i];
        int li = u.p2.lab[i];
        float ai = u.p2.ar[i];
        unsigned long long m = 0ull;
        for (int tb = 0; tb < 64; tb++) {
            int j = w * 64 + tb;
            if (j < KC && j > i && u.p2.lab[j] == li) {
                float4 bj = u.p2.bx[j];
                float ltx = fmaxf(bi.x, bj.x), lty = fmaxf(bi.y, bj.y);
                float rbx = fminf(bi.z, bj.z), rby = fminf(bi.w, bj.w);
                float iw = fmaxf(rbx - ltx, 0.f), ih = fmaxf(rby - lty, 0.f);
                float inter = iw * ih;
                float iou = inter / (ai + u.p2.ar[j] - inter + 1e-9f);
                if (iou > NMS_T) m |= (1ull << tb);
            }
        }
        u.p2.msk[t] = m;
    }
    __syncthreads();

    // ---- I: active-row NMS scan (only rows with nonzero masks matter) ----
    for (int i = tid; i < KC; i += 1024) {
        unsigned long long nz = u.p2.msk[i * 5] | u.p2.msk[i * 5 + 1] | u.p2.msk[i * 5 + 2] |
                                u.p2.msk[i * 5 + 3] | u.p2.msk[i * 5 + 4];
        if (nz) atomicOr(&u.p2.actw[i >> 5], 1u << (i & 31));
    }
    __syncthreads();
    if (tid == 0) {
        u.p2.keep[0] = u.p2.keep[1] = u.p2.keep[2] = u.p2.keep[3] = u.p2.keep[4] = ~0ull;
        for (int w = 0; w < 10; w++) {
            unsigned int mw = u.p2.actw[w];
            while (mw) {
                int bpos = __ffs(mw) - 1;
                mw &= mw - 1;
                int i = w * 32 + bpos;   // ascending i
                if ((u.p2.keep[i >> 6] >> (i & 63)) & 1ull) {
#pragma unroll
                    for (int r = 0; r < 5; r++) u.p2.keep[r] &= ~u.p2.msk[i * 5 + r];
                }
            }
        }
        int s = 0;
        for (int w = 0; w < 5; w++) {
            unsigned long long kw = u.p2.keep[w];
            if (w == 4) kw &= (1ull << 44) - 1ull;   // bits >= KC excluded
            u.p2.wpref[w] = s;
            s += (int)__popcll(kw);
        }
        u.p2.wpref[5] = s;
    }
    __syncthreads();

    // rank kept (index asc == score desc) then non-kept (index asc) via popcounts
    if (tid < KC) {
        int w = tid >> 6, bp = tid & 63;
        unsigned long long kw = u.p2.keep[w];
        bool kept = (kw >> bp) & 1ull;
        int r = u.p2.wpref[w] + (int)__popcll(kw & ((1ull << bp) - 1ull));
        if (kept) {
            if (r < DET) { u.p2.order[r] = tid; u.p2.okept[r] = 1; }
        } else {
            int nr = u.p2.wpref[5] + (tid - r);
            if (nr < DET) { u.p2.order[nr] = tid; u.p2.okept[nr] = 0; }
        }
    }
    __syncthreads();

    if (tid < DET) {
        int o = u.p2.order[tid];
        float scale = scalef[b];
        float4 bb = u.p2.bx[o];
        float s = (u.p2.okept[tid] && o < valid) ? u.p2.sc2[o] : 0.f;
        float lb = (o < valid) ? (float)u.p2.lab[o] : 0.f;
        float* po = out + ((size_t)b * DET + tid) * 6;
        po[0] = bb.x / scale;
        po[1] = bb.y / scale;
        po[2] = bb.z / scale;
        po[3] = bb.w / scale;
        po[4] = s;
        po[5] = lb;
    }
}

extern "C" void kernel_launch(void* const* d_in, const int* in_sizes, int n_in,
                              void* d_out, int out_size, void* d_ws, size_t ws_size,
                              hipStream_t stream) {
    const float* p3 = (const float*)d_in[0];
    const float* p4 = (const float*)d_in[1];
    const float* p5 = (const float*)d_in[2];
    const float* anchors = (const float*)d_in[3];
    const int* imshapes = (const int*)d_in[4];
    const float* scalef = (const float*)d_in[5];
    float* out = (float*)d_out;

    float* gmax = (float*)d_ws;   // [16][25200] floats, fully written by k_max each launch

    k_max<<<TOTCH / CPB, 256, 0, stream>>>(p3, p4, p5, gmax);
    k_img<<<BATCH, 1024, 0, stream>>>(p3, p4, p5, anchors, imshapes, scalef, gmax, out);
}